// Round 19
// baseline (1873.399 us; speedup 1.0000x reference)
//
#include <hip/hip_runtime.h>
#include <stdint.h>

typedef __attribute__((ext_vector_type(4))) float f32x4;
typedef _Float16 f16x8 __attribute__((ext_vector_type(8)));
typedef __attribute__((ext_vector_type(8))) unsigned short u16x8;
typedef __attribute__((ext_vector_type(2))) unsigned int u32x2;
typedef unsigned short u16;
typedef unsigned int u32;

#define LSEQ 8192
#define BB 8
#define DD 1024
#define MM 65536      // B*L
#define NCH 128       // chunks per sequence (L/64)

__device__ __forceinline__ u16 f2h(float f) {
    _Float16 h = (_Float16)f;
    return *(u16*)&h;
}
__device__ __forceinline__ float h2f(u16 u) {
    _Float16 h = *(_Float16*)&u;
    return (float)h;
}

__device__ __forceinline__ void gload_lds16(const void* g, void* l) {
    __builtin_amdgcn_global_load_lds(
        (const __attribute__((address_space(1))) u32*)g,
        (__attribute__((address_space(3))) u32*)l, 16, 0, 0);
}

// ---------------- conv + silu + transpose -> xb f16 [B*L][D] ----------------
__global__ __launch_bounds__(256) void k_conv_silu(const float* __restrict__ x,
                                                   const float* __restrict__ w,
                                                   u16* __restrict__ xb) {
    int m = blockIdx.x;              // m = b*L + l
    int b = m >> 13, l = m & 8191;
    int d0 = threadIdx.x * 4;
    f32x4 wv[4];
#pragma unroll
    for (int j = 0; j < 4; j++) wv[j] = *(const f32x4*)&w[(d0 + j) * 4];
    float acc[4] = {0.f, 0.f, 0.f, 0.f};
#pragma unroll
    for (int kk = 0; kk < 4; kk++) {
        int lp = l - 3 + kk;
        if (lp >= 0) {
            f32x4 xv = *(const f32x4*)&x[((size_t)(lp * BB + b)) * DD + d0];
#pragma unroll
            for (int j = 0; j < 4; j++) acc[j] += xv[j] * wv[j][kk];
        }
    }
    u16 o[4];
#pragma unroll
    for (int j = 0; j < 4; j++) {
        float a = acc[j];
        o[j] = f2h(a / (1.f + __expf(-a)));
    }
    u32x2 pk;
    pk.x = (u32)o[0] | ((u32)o[1] << 16);
    pk.y = (u32)o[2] | ((u32)o[3] << 16);
    *(u32x2*)&xb[(size_t)m * DD + d0] = pk;
}

// ---------------- pack weights into B^T f16 layouts ----------------
__global__ __launch_bounds__(256) void k_packW(const float* __restrict__ Wq,
                                               const float* __restrict__ Wkg,
                                               const float* __restrict__ Wv,
                                               const float* __restrict__ Wg,
                                               const float* __restrict__ Wout,
                                               u16* __restrict__ Wcat,
                                               u16* __restrict__ WoutT) {
    int idx = blockIdx.x * 256 + threadIdx.x;
    const int T1 = 3072 * 1024;
    if (idx < T1) {
        int n = idx >> 10, kk = idx & 1023;
        float v;
        if (n < 512)        v = Wq [kk * 512 + n];
        else if (n < 1024)  v = Wkg[kk * 512 + (n - 512)];
        else if (n < 2048)  v = Wv [kk * 1024 + (n - 1024)];
        else                v = Wg [kk * 1024 + (n - 2048)];
        Wcat[idx] = f2h(v);
    } else {
        int j = idx - T1;
        if (j < 1024 * 1024) {
            int n = j >> 10, kk = j & 1023;
            WoutT[j] = f2h(Wout[kk * 1024 + n]);
        }
    }
}

// per-fragment epilogue (4 rows x 1 col-group of 16 handled by caller's lr)
template <int MODE>
__device__ __forceinline__ void epi_frag(f32x4 v, int grow0, int gcol,
                                         u16* __restrict__ qo, u16* __restrict__ gko,
                                         u16* __restrict__ ko, u16* __restrict__ vo,
                                         u16* __restrict__ sgo, const float* __restrict__ bg,
                                         float* __restrict__ out) {
#pragma unroll
    for (int rr = 0; rr < 4; rr++) {
        int grow = grow0 + rr;
        float val = v[rr];
        if (MODE == 1) {
            if (gcol < 512) {
                qo[(size_t)grow * 512 + gcol] = f2h(val);
            } else if (gcol < 1024) {
                float ls = fminf(val, 0.f) - log1pf(__expf(-fabsf(val)));
                float gkv = ls * 0.0625f;
                gko[(size_t)grow * 512 + (gcol - 512)] = f2h(gkv);
                ko [(size_t)grow * 512 + (gcol - 512)] = f2h(-expm1f(gkv));
            } else if (gcol < 2048) {
                vo[(size_t)grow * 1024 + (gcol - 1024)] = f2h(val);
            } else {
                float gg = val + bg[gcol - 2048];
                sgo[(size_t)grow * 1024 + (gcol - 2048)] = f2h(gg / (1.f + __expf(-gg)));
            }
        } else {
            int l = grow & 8191, b = grow >> 13;
            out[((size_t)(l * BB + b)) * DD + gcol] = val;
        }
    }
}

// ---------------- f16 GEMM, C = A[M][K] * Bt[N][K]^T, 256x64 tile, BK=32 ----------------
// (R18 structure: conflicts 0, Occ 44%, ~700us — latency/VALU-floored; frozen)
template <int MODE>
__global__ __launch_bounds__(256, 3) void k_gemm_bt(
    const u16* __restrict__ A, const u16* __restrict__ Bt, int nt_tiles,
    u16* __restrict__ qo, u16* __restrict__ gko, u16* __restrict__ ko,
    u16* __restrict__ vo, u16* __restrict__ sgo, const float* __restrict__ bg,
    float* __restrict__ out) {
    const int K = 1024;
    __shared__ __align__(16) u16 Sm[20480];   // 40 KB: 2 bufs x (A 16KB | B 4KB)
    int tid = threadIdx.x;
    int w = tid >> 6, lane = tid & 63;
    int wm = w >> 1, wn = w & 1;
    int lr = lane & 15, lk = lane >> 4;

    // XCD-aware 2D-blocked tile mapping
    int xcd = blockIdx.x & 7;
    int cidx = blockIdx.x >> 3;
    int grpsz = nt_tiles * 4;
    int grp = cidx / grpsz;
    int r = cidx - grp * grpsz;
    int ntile = r >> 2;
    int mts_per_chunk = (gridDim.x >> 3) / nt_tiles;   // 32
    int mtile = xcd * mts_per_chunk + grp * 4 + (r & 3);
    int m0 = mtile << 8, n0 = ntile << 6;

#define DECL_ACC(MT) f32x4 a##MT##_0 = {0.f,0.f,0.f,0.f}, a##MT##_1 = {0.f,0.f,0.f,0.f};
    DECL_ACC(0) DECL_ACC(1) DECL_ACC(2) DECL_ACC(3)
    DECL_ACC(4) DECL_ACC(5) DECL_ACC(6) DECL_ACC(7)
#undef DECL_ACC

    // staging: thread -> row tid>>2, slot tid&3; src slot pre-XOR'd with (row>>1)&3
    int row = tid >> 2;
    int sslot = (tid & 3) ^ ((tid >> 3) & 3);
    const u16* gA = A + (size_t)(m0 + row) * K + sslot * 8;
    const u16* gB = Bt + (size_t)(n0 + row) * K + sslot * 8;   // rows 0..63
    char* lA = (char*)Sm + w * 1024;            // HW adds lane*16
    char* lB = (char*)Sm + 16384 + w * 1024;    // B region base = byte 16384

// 5 gloads: A rows +0/+64/+128/+192 (4 x 4KB), B rows 0..63 (1 x 4KB)
#define STAGE(TT, OB) { \
    int k1 = (TT) << 5; \
    gload_lds16(gA + k1, lA + (OB)); \
    gload_lds16(gA + (size_t)64 * K + k1, lA + (OB) + 4096); \
    gload_lds16(gA + (size_t)128 * K + k1, lA + (OB) + 8192); \
    gload_lds16(gA + (size_t)192 * K + k1, lA + (OB) + 12288); \
    gload_lds16(gB + k1, lB + (OB)); }

#define MFMA_ROW(MT) { \
    f16x8 av = *(const f16x8*)&As[(wm * 128 + MT * 16 + lr) * 32 + acsl]; \
    a##MT##_0 = __builtin_amdgcn_mfma_f32_16x16x32_f16(av, b0, a##MT##_0, 0, 0, 0); \
    a##MT##_1 = __builtin_amdgcn_mfma_f32_16x16x32_f16(av, b1, a##MT##_1, 0, 0, 0); }

#define COMPUTE() { \
    int acsl = (lk ^ ((lr >> 1) & 3)) * 8; \
    f16x8 b0 = *(const f16x8*)&Bs[(wn * 32 +  0 + lr) * 32 + acsl]; \
    f16x8 b1 = *(const f16x8*)&Bs[(wn * 32 + 16 + lr) * 32 + acsl]; \
    __builtin_amdgcn_s_setprio(1); \
    MFMA_ROW(0) MFMA_ROW(1) MFMA_ROW(2) MFMA_ROW(3) \
    MFMA_ROW(4) MFMA_ROW(5) MFMA_ROW(6) MFMA_ROW(7) \
    __builtin_amdgcn_s_setprio(0); }

    // prologue: stage K-tiles 0 and 1 (10 loads in flight per thread)
    STAGE(0, 0)
    STAGE(1, 20480)

    for (int t = 0; t < 31; ++t) {
        // wait own stage(t) loads only; stage(t+1)'s 5 stay in flight
        asm volatile("s_waitcnt vmcnt(5)" ::: "memory");
        __builtin_amdgcn_sched_barrier(0);
        __builtin_amdgcn_s_barrier();   // all waves' tile-t writes landed
        {
            const u16* As = Sm + (t & 1) * 10240;
            const u16* Bs = As + 8192;
            COMPUTE()
        }
        __builtin_amdgcn_s_barrier();   // buf(t&1) fully consumed
        __builtin_amdgcn_sched_barrier(0);
        if (t < 30) {
            STAGE(t + 2, (t & 1) * 20480)
        }
    }
    // tile 31 (buf 1): everything must be in
    asm volatile("s_waitcnt vmcnt(0)" ::: "memory");
    __builtin_amdgcn_sched_barrier(0);
    __builtin_amdgcn_s_barrier();
    {
        const u16* As = Sm + 10240;
        const u16* Bs = As + 8192;
        COMPUTE()
    }
#undef COMPUTE
#undef MFMA_ROW
#undef STAGE

#define EPI_ROW(MT) { \
    int gr0 = m0 + wm * 128 + MT * 16 + lk * 4; \
    epi_frag<MODE>(a##MT##_0, gr0, n0 + wn * 32 +  0 + lr, qo, gko, ko, vo, sgo, bg, out); \
    epi_frag<MODE>(a##MT##_1, gr0, n0 + wn * 32 + 16 + lr, qo, gko, ko, vo, sgo, bg, out); }
    EPI_ROW(0) EPI_ROW(1) EPI_ROW(2) EPI_ROW(3)
    EPI_ROW(4) EPI_ROW(5) EPI_ROW(6) EPI_ROW(7)
#undef EPI_ROW
}

// ---------------- pass1: per-chunk increment M_c = sum_s k_s e^{G_C - G_s} v_s^T ----------------
__global__ __launch_bounds__(64) void k_pass1(const u16* __restrict__ gkb,
                                              const u16* __restrict__ kb,
                                              const u16* __restrict__ vb,
                                              float* __restrict__ Mo,
                                              float* __restrict__ eGC) {
    __shared__ __align__(16) float kkT[64 * 32];  // [t][i] fp32
    int bhc = blockIdx.x;
    int c = bhc & 127, bh = bhc >> 7;
    int h = bh & 15, b = bh >> 4;
    int m0 = b * LSEQ + c * 64;
    int lane = threadIdx.x;
    if (lane < 32) {
        int i = lane;
        size_t base = (size_t)m0 * 512 + h * 32 + i;
        float G = 0.f;
        for (int t = 0; t < 64; t++) {
            G += h2f(gkb[base + (size_t)t * 512]);
            G = fmaxf(G, -60.f);
            kkT[t * 32 + i] = h2f(kb[base + (size_t)t * 512]) * __expf(-G);
        }
        eGC[bhc * 32 + i] = __expf(G);
    }
    __syncthreads();
    float Ma[32];
#pragma unroll
    for (int i = 0; i < 32; i++) Ma[i] = 0.f;
    size_t vbase = (size_t)m0 * 1024 + h * 64 + lane;
    for (int t = 0; t < 64; t++) {
        float vj = h2f(vb[vbase + (size_t)t * 1024]);
#pragma unroll
        for (int i4 = 0; i4 < 32; i4 += 4) {
            f32x4 kk4 = *(const f32x4*)&kkT[t * 32 + i4];
            Ma[i4 + 0] += kk4[0] * vj;
            Ma[i4 + 1] += kk4[1] * vj;
            Ma[i4 + 2] += kk4[2] * vj;
            Ma[i4 + 3] += kk4[3] * vj;
        }
    }
    size_t mb = (size_t)bhc * 2048 + lane;
#pragma unroll
    for (int i = 0; i < 32; i++) Mo[mb + i * 64] = Ma[i];
}

// ---------------- pass2: chunk-level recurrence, i-rows split across 4 blocks ----------------
__global__ __launch_bounds__(64) void k_pass2(float* Mbuf, float* Sbuf,
                                              const float* __restrict__ eGC,
                                              float* __restrict__ state_out, int aliased) {
    int blk = blockIdx.x;
    int bh = blk >> 2, iq = blk & 3;
    int i0 = iq * 8;
    int j = threadIdx.x;
    float S[8];
#pragma unroll
    for (int i = 0; i < 8; i++) S[i] = 0.f;
    for (int c = 0; c < NCH; c++) {
        size_t base = ((size_t)bh * NCH + c) * 2048;
        float mv[8], ev[8];
#pragma unroll
        for (int i = 0; i < 8; i++) mv[i] = Mbuf[base + (i0 + i) * 64 + j];
#pragma unroll
        for (int i = 0; i < 8; i++) ev[i] = eGC[(bh * NCH + c) * 32 + i0 + i];
        if (aliased) { asm volatile("s_waitcnt vmcnt(0)" ::: "memory"); }
#pragma unroll
        for (int i = 0; i < 8; i++) Sbuf[base + (i0 + i) * 64 + j] = S[i];  // chunk-START state
#pragma unroll
        for (int i = 0; i < 8; i++) S[i] = (S[i] + mv[i]) * ev[i];
    }
    size_t so = (size_t)bh * 2048 + j;
#pragma unroll
    for (int i = 0; i < 8; i++) state_out[so + (i0 + i) * 64] = S[i];
}

// ---------------- pass3: intra-chunk outputs + aug + groupnorm + silu-gate ----------------
// R18 post-mortem: pass3 (~450us) is the largest non-GEMM1 item; serial 64-iter
// t-loop on ONE wave was latency-bound. R19: 4 waves/chunk, wave w owns
// t in [16w,16w+16). Waves 1..3 each build ONE quarter-increment Q_{w-1} =
// sum_{s in [16(w-1),16w)} kk_s v_s^T into LDS; after barrier, wave w inits
// T = S_c + Q_0..Q_{w-1} and runs 16 full iterations (critical path 64->~32).
// Aug phase split across waves 1-2; serial-G stays on wave 0.
__global__ __launch_bounds__(256) void k_pass3(const u16* __restrict__ qb,
                                               const u16* __restrict__ gkb,
                                               const u16* __restrict__ kb,
                                               const u16* __restrict__ vb,
                                               const u16* __restrict__ sgb,
                                               const float* __restrict__ Sbuf,
                                               const float* __restrict__ aug,
                                               u16* __restrict__ PRE) {
    __shared__ __align__(16) u16 qqT[64 * 32];  // [t][i] f16, 4KB
    __shared__ __align__(16) u16 kkT[64 * 32];  // 4KB
    __shared__ float awl[64];
    __shared__ __align__(16) float Qbuf[3][32][64];  // 24KB
    int bhc = blockIdx.x;
    int c = bhc & 127, bh = bhc >> 7;
    int h = bh & 15, b = bh >> 4;
    int m0 = b * LSEQ + c * 64;
    int tid = threadIdx.x;
    int wv = tid >> 6, lane = tid & 63;
    const float scale = 0.17677669529663689f;  // 1/sqrt(32)
    // phase 1a: serial-G transform (wave 0, 32 lanes; G prefix serial in t)
    if (wv == 0 && lane < 32) {
        int i = lane;
        size_t base = (size_t)m0 * 512 + h * 32 + i;
        float G = 0.f;
        for (int t = 0; t < 64; t++) {
            float gkv = h2f(gkb[base + (size_t)t * 512]);
            float qv  = h2f(qb [base + (size_t)t * 512]);
            float kv  = h2f(kb [base + (size_t)t * 512]);
            G += gkv;
            G = fmaxf(G, -60.f);
            qqT[t * 32 + i] = f2h(qv * __expf(G) * scale);
            kkT[t * 32 + i] = f2h(kv * __expf(-G));
        }
    }
    // phase 1b: aug weights on waves 1-2 (each handles 16 tt's -> 32 t's)
    if (wv == 1 || wv == 2) {
        int i = lane & 31;
        int th = (lane >> 5) << 5;     // 0 or 32
        float augi = aug[h * 32 + i];
        size_t base2 = (size_t)m0 * 512 + h * 32 + i;
        int tt0 = (wv - 1) * 16;
        for (int tt = tt0; tt < tt0 + 16; tt++) {
            int t = tt + th;
            float qv = h2f(qb[base2 + (size_t)t * 512]);
            float kv = h2f(kb[base2 + (size_t)t * 512]);
            float p = qv * kv * augi;
            p += __shfl_xor(p, 1);
            p += __shfl_xor(p, 2);
            p += __shfl_xor(p, 4);
            p += __shfl_xor(p, 8);
            p += __shfl_xor(p, 16);
            if (i == 0) awl[t] = p;
        }
    }
    __syncthreads();
    size_t vbase = (size_t)m0 * 1024 + h * 64 + lane;
    // Q-phase: wave w>=1 computes Q_{w-1} over s in [16(w-1), 16w)
    if (wv >= 1) {
        int s0 = (wv - 1) * 16;
        float Q[32];
#pragma unroll
        for (int i = 0; i < 32; i++) Q[i] = 0.f;
        for (int s = s0; s < s0 + 16; s++) {
            float vj = h2f(vb[vbase + (size_t)s * 1024]);
            u16x8 k8a = *(const u16x8*)&kkT[s * 32 + 0];
            u16x8 k8b = *(const u16x8*)&kkT[s * 32 + 8];
            u16x8 k8c = *(const u16x8*)&kkT[s * 32 + 16];
            u16x8 k8d = *(const u16x8*)&kkT[s * 32 + 24];
#pragma unroll
            for (int e = 0; e < 8; e++) {
                Q[e]      += h2f(k8a[e]) * vj;
                Q[8 + e]  += h2f(k8b[e]) * vj;
                Q[16 + e] += h2f(k8c[e]) * vj;
                Q[24 + e] += h2f(k8d[e]) * vj;
            }
        }
#pragma unroll
        for (int i = 0; i < 32; i++) Qbuf[wv - 1][i][lane] = Q[i];
    }
    __syncthreads();
    // T init: chunk-start state + preceding quarter-increments
    float T[32];
    size_t sb = (size_t)bhc * 2048 + lane;
#pragma unroll
    for (int i = 0; i < 32; i++) T[i] = Sbuf[sb + i * 64];
    for (int w2 = 0; w2 < wv; w2++) {
#pragma unroll
        for (int i = 0; i < 32; i++) T[i] += Qbuf[w2][i][lane];
    }
    // main loop: 16 t's per wave
    int t0 = wv * 16;
    for (int t = t0; t < t0 + 16; t++) {
        float vj  = h2f(vb [vbase + (size_t)t * 1024]);
        float sgj = h2f(sgb[vbase + (size_t)t * 1024]);
        float aw = awl[t];
        float o0 = 0.f, o1 = 0.f, o2 = 0.f, o3 = 0.f;
        u16x8 kk8a = *(const u16x8*)&kkT[t * 32 + 0];
        u16x8 qq8a = *(const u16x8*)&qqT[t * 32 + 0];
        u16x8 kk8b = *(const u16x8*)&kkT[t * 32 + 8];
        u16x8 qq8b = *(const u16x8*)&qqT[t * 32 + 8];
        u16x8 kk8c = *(const u16x8*)&kkT[t * 32 + 16];
        u16x8 qq8c = *(const u16x8*)&qqT[t * 32 + 16];
        u16x8 kk8d = *(const u16x8*)&kkT[t * 32 + 24];
        u16x8 qq8d = *(const u16x8*)&qqT[t * 32 + 24];
#pragma unroll
        for (int e = 0; e < 8; e++) {
            T[e]      += h2f(kk8a[e]) * vj;  o0 += h2f(qq8a[e]) * T[e];
            T[8 + e]  += h2f(kk8b[e]) * vj;  o1 += h2f(qq8b[e]) * T[8 + e];
            T[16 + e] += h2f(kk8c[e]) * vj;  o2 += h2f(qq8c[e]) * T[16 + e];
            T[24 + e] += h2f(kk8d[e]) * vj;  o3 += h2f(qq8d[e]) * T[24 + e];
        }
        float o = (o0 + o1) + (o2 + o3);
        o += 1.f / (1.f + __expf(-aw * vj));       // + sigmoid(aug_w * v)
        // group norm over dv=64 (all 64 lanes of this wave share t)
        float s1 = o, s2 = o * o;
#pragma unroll
        for (int msk = 1; msk < 64; msk <<= 1) {
            s1 += __shfl_xor(s1, msk);
            s2 += __shfl_xor(s2, msk);
        }
        float mu = s1 * 0.015625f;
        float var = s2 * 0.015625f - mu * mu;
        float on = (o - mu) * rsqrtf(fmaxf(var, 0.f) + 1e-5f);
        PRE[vbase + (size_t)t * 1024] = f2h(on * sgj);
    }
}

// ---------------- host launch ----------------
extern "C" void kernel_launch(void* const* d_in, const int* in_sizes, int n_in,
                              void* d_out, int out_size, void* d_ws, size_t ws_size,
                              hipStream_t stream) {
    (void)in_sizes; (void)n_in; (void)out_size;
    const float* x      = (const float*)d_in[0];
    const float* conv_w = (const float*)d_in[1];
    const float* Wq     = (const float*)d_in[2];
    const float* Wkg    = (const float*)d_in[3];
    const float* Wv     = (const float*)d_in[4];
    const float* Wg     = (const float*)d_in[5];
    const float* bg     = (const float*)d_in[6];
    const float* Wout   = (const float*)d_in[7];
    const float* aug    = (const float*)d_in[8];

    char* ws = (char*)d_ws;
    u16*   xb    = (u16*)  (ws + 0);            // 134217728 B (also PRE later)
    u16*   Wcat  = (u16*)  (ws + 134217728);    //   6291456
    u16*   WoutT = (u16*)  (ws + 140509184);    //   2097152
    u16*   qb    = (u16*)  (ws + 142606336);    //  67108864
    u16*   gkb   = (u16*)  (ws + 209715200);    //  67108864
    u16*   kbuf  = (u16*)  (ws + 276824064);    //  67108864
    u16*   sgb   = (u16*)  (ws + 343932928);    // 134217728
    float* Mbuf  = (float*)(ws + 478150656);    // 134217728
    float* eGC   = (float*)(ws + 612368384);    //   2097152
    float* Sb    = (float*)(ws + 614465536);    // 134217728 (optional)
    const size_t REQ_FULL = 748683264ull;
    int aliased = (ws_size < REQ_FULL) ? 1 : 0;
    float* Sbuf = aliased ? Mbuf : Sb;

    float* out = (float*)d_out;
    float* state_out = out + 67108864;
    u16* vb = (u16*)d_out;  // v (f16) lives in out region until GEMM2 overwrites it

    k_conv_silu<<<dim3(65536), dim3(256), 0, stream>>>(x, conv_w, xb);
    k_packW<<<dim3(16384), dim3(256), 0, stream>>>(Wq, Wkg, Wv, Wg, Wout, Wcat, WoutT);
    k_gemm_bt<1><<<dim3(12288), dim3(256), 0, stream>>>(xb, Wcat, 48,
                                                        qb, gkb, kbuf, vb, sgb, bg, nullptr);
    k_pass1<<<dim3(16384), dim3(64), 0, stream>>>(gkb, kbuf, vb, Mbuf, eGC);
    k_pass2<<<dim3(512), dim3(64), 0, stream>>>(Mbuf, Sbuf, eGC, state_out, aliased);
    k_pass3<<<dim3(16384), dim3(256), 0, stream>>>(qb, gkb, kbuf, vb, sgb, Sbuf, aug, xb /*PRE*/);
    k_gemm_bt<2><<<dim3(4096), dim3(256), 0, stream>>>(xb, WoutT, 16,
                                                       nullptr, nullptr, nullptr, nullptr, nullptr, nullptr, out);
}

// Round 20
// 1683.784 us; speedup vs baseline: 1.1126x; 1.1126x over previous
//
#include <hip/hip_runtime.h>
#include <stdint.h>

typedef __attribute__((ext_vector_type(4))) float f32x4;
typedef _Float16 f16x8 __attribute__((ext_vector_type(8)));
typedef __attribute__((ext_vector_type(8))) unsigned short u16x8;
typedef __attribute__((ext_vector_type(2))) unsigned int u32x2;
typedef unsigned short u16;
typedef unsigned int u32;

#define LSEQ 8192
#define BB 8
#define DD 1024
#define MM 65536      // B*L
#define NCH 128       // chunks per sequence (L/64)

__device__ __forceinline__ u16 f2h(float f) {
    _Float16 h = (_Float16)f;
    return *(u16*)&h;
}
__device__ __forceinline__ float h2f(u16 u) {
    _Float16 h = *(_Float16*)&u;
    return (float)h;
}

__device__ __forceinline__ void gload_lds16(const void* g, void* l) {
    __builtin_amdgcn_global_load_lds(
        (const __attribute__((address_space(1))) u32*)g,
        (__attribute__((address_space(3))) u32*)l, 16, 0, 0);
}

// ---------------- conv + silu + transpose -> xb f16 [B*L][D] ----------------
__global__ __launch_bounds__(256) void k_conv_silu(const float* __restrict__ x,
                                                   const float* __restrict__ w,
                                                   u16* __restrict__ xb) {
    int m = blockIdx.x;              // m = b*L + l
    int b = m >> 13, l = m & 8191;
    int d0 = threadIdx.x * 4;
    f32x4 wv[4];
#pragma unroll
    for (int j = 0; j < 4; j++) wv[j] = *(const f32x4*)&w[(d0 + j) * 4];
    float acc[4] = {0.f, 0.f, 0.f, 0.f};
#pragma unroll
    for (int kk = 0; kk < 4; kk++) {
        int lp = l - 3 + kk;
        if (lp >= 0) {
            f32x4 xv = *(const f32x4*)&x[((size_t)(lp * BB + b)) * DD + d0];
#pragma unroll
            for (int j = 0; j < 4; j++) acc[j] += xv[j] * wv[j][kk];
        }
    }
    u16 o[4];
#pragma unroll
    for (int j = 0; j < 4; j++) {
        float a = acc[j];
        o[j] = f2h(a / (1.f + __expf(-a)));
    }
    u32x2 pk;
    pk.x = (u32)o[0] | ((u32)o[1] << 16);
    pk.y = (u32)o[2] | ((u32)o[3] << 16);
    *(u32x2*)&xb[(size_t)m * DD + d0] = pk;
}

// ---------------- pack weights into B^T f16 layouts ----------------
__global__ __launch_bounds__(256) void k_packW(const float* __restrict__ Wq,
                                               const float* __restrict__ Wkg,
                                               const float* __restrict__ Wv,
                                               const float* __restrict__ Wg,
                                               const float* __restrict__ Wout,
                                               u16* __restrict__ Wcat,
                                               u16* __restrict__ WoutT) {
    int idx = blockIdx.x * 256 + threadIdx.x;
    const int T1 = 3072 * 1024;
    if (idx < T1) {
        int n = idx >> 10, kk = idx & 1023;
        float v;
        if (n < 512)        v = Wq [kk * 512 + n];
        else if (n < 1024)  v = Wkg[kk * 512 + (n - 512)];
        else if (n < 2048)  v = Wv [kk * 1024 + (n - 1024)];
        else                v = Wg [kk * 1024 + (n - 2048)];
        Wcat[idx] = f2h(v);
    } else {
        int j = idx - T1;
        if (j < 1024 * 1024) {
            int n = j >> 10, kk = j & 1023;
            WoutT[j] = f2h(Wout[kk * 1024 + n]);
        }
    }
}

// per-fragment epilogue (4 rows x 1 col-group of 16 handled by caller's lr)
template <int MODE>
__device__ __forceinline__ void epi_frag(f32x4 v, int grow0, int gcol,
                                         u16* __restrict__ qo, u16* __restrict__ gko,
                                         u16* __restrict__ ko, u16* __restrict__ vo,
                                         u16* __restrict__ sgo, const float* __restrict__ bg,
                                         float* __restrict__ out) {
#pragma unroll
    for (int rr = 0; rr < 4; rr++) {
        int grow = grow0 + rr;
        float val = v[rr];
        if (MODE == 1) {
            if (gcol < 512) {
                qo[(size_t)grow * 512 + gcol] = f2h(val);
            } else if (gcol < 1024) {
                float ls = fminf(val, 0.f) - log1pf(__expf(-fabsf(val)));
                float gkv = ls * 0.0625f;
                gko[(size_t)grow * 512 + (gcol - 512)] = f2h(gkv);
                ko [(size_t)grow * 512 + (gcol - 512)] = f2h(-expm1f(gkv));
            } else if (gcol < 2048) {
                vo[(size_t)grow * 1024 + (gcol - 1024)] = f2h(val);
            } else {
                float gg = val + bg[gcol - 2048];
                sgo[(size_t)grow * 1024 + (gcol - 2048)] = f2h(gg / (1.f + __expf(-gg)));
            }
        } else {
            int l = grow & 8191, b = grow >> 13;
            out[((size_t)(l * BB + b)) * DD + gcol] = val;
        }
    }
}

// ---------------- f16 GEMM, C = A[M][K] * Bt[N][K]^T, 256x64 tile, BK=32 ----------------
// (R18 structure: conflicts 0, Occ 44%, ~700us — latency/VALU-floored; frozen)
template <int MODE>
__global__ __launch_bounds__(256, 3) void k_gemm_bt(
    const u16* __restrict__ A, const u16* __restrict__ Bt, int nt_tiles,
    u16* __restrict__ qo, u16* __restrict__ gko, u16* __restrict__ ko,
    u16* __restrict__ vo, u16* __restrict__ sgo, const float* __restrict__ bg,
    float* __restrict__ out) {
    const int K = 1024;
    __shared__ __align__(16) u16 Sm[20480];   // 40 KB: 2 bufs x (A 16KB | B 4KB)
    int tid = threadIdx.x;
    int w = tid >> 6, lane = tid & 63;
    int wm = w >> 1, wn = w & 1;
    int lr = lane & 15, lk = lane >> 4;

    // XCD-aware 2D-blocked tile mapping
    int xcd = blockIdx.x & 7;
    int cidx = blockIdx.x >> 3;
    int grpsz = nt_tiles * 4;
    int grp = cidx / grpsz;
    int r = cidx - grp * grpsz;
    int ntile = r >> 2;
    int mts_per_chunk = (gridDim.x >> 3) / nt_tiles;   // 32
    int mtile = xcd * mts_per_chunk + grp * 4 + (r & 3);
    int m0 = mtile << 8, n0 = ntile << 6;

#define DECL_ACC(MT) f32x4 a##MT##_0 = {0.f,0.f,0.f,0.f}, a##MT##_1 = {0.f,0.f,0.f,0.f};
    DECL_ACC(0) DECL_ACC(1) DECL_ACC(2) DECL_ACC(3)
    DECL_ACC(4) DECL_ACC(5) DECL_ACC(6) DECL_ACC(7)
#undef DECL_ACC

    // staging: thread -> row tid>>2, slot tid&3; src slot pre-XOR'd with (row>>1)&3
    int row = tid >> 2;
    int sslot = (tid & 3) ^ ((tid >> 3) & 3);
    const u16* gA = A + (size_t)(m0 + row) * K + sslot * 8;
    const u16* gB = Bt + (size_t)(n0 + row) * K + sslot * 8;   // rows 0..63
    char* lA = (char*)Sm + w * 1024;            // HW adds lane*16
    char* lB = (char*)Sm + 16384 + w * 1024;    // B region base = byte 16384

// 5 gloads: A rows +0/+64/+128/+192 (4 x 4KB), B rows 0..63 (1 x 4KB)
#define STAGE(TT, OB) { \
    int k1 = (TT) << 5; \
    gload_lds16(gA + k1, lA + (OB)); \
    gload_lds16(gA + (size_t)64 * K + k1, lA + (OB) + 4096); \
    gload_lds16(gA + (size_t)128 * K + k1, lA + (OB) + 8192); \
    gload_lds16(gA + (size_t)192 * K + k1, lA + (OB) + 12288); \
    gload_lds16(gB + k1, lB + (OB)); }

#define MFMA_ROW(MT) { \
    f16x8 av = *(const f16x8*)&As[(wm * 128 + MT * 16 + lr) * 32 + acsl]; \
    a##MT##_0 = __builtin_amdgcn_mfma_f32_16x16x32_f16(av, b0, a##MT##_0, 0, 0, 0); \
    a##MT##_1 = __builtin_amdgcn_mfma_f32_16x16x32_f16(av, b1, a##MT##_1, 0, 0, 0); }

#define COMPUTE() { \
    int acsl = (lk ^ ((lr >> 1) & 3)) * 8; \
    f16x8 b0 = *(const f16x8*)&Bs[(wn * 32 +  0 + lr) * 32 + acsl]; \
    f16x8 b1 = *(const f16x8*)&Bs[(wn * 32 + 16 + lr) * 32 + acsl]; \
    __builtin_amdgcn_s_setprio(1); \
    MFMA_ROW(0) MFMA_ROW(1) MFMA_ROW(2) MFMA_ROW(3) \
    MFMA_ROW(4) MFMA_ROW(5) MFMA_ROW(6) MFMA_ROW(7) \
    __builtin_amdgcn_s_setprio(0); }

    // prologue: stage K-tiles 0 and 1 (10 loads in flight per thread)
    STAGE(0, 0)
    STAGE(1, 20480)

    for (int t = 0; t < 31; ++t) {
        // wait own stage(t) loads only; stage(t+1)'s 5 stay in flight
        asm volatile("s_waitcnt vmcnt(5)" ::: "memory");
        __builtin_amdgcn_sched_barrier(0);
        __builtin_amdgcn_s_barrier();   // all waves' tile-t writes landed
        {
            const u16* As = Sm + (t & 1) * 10240;
            const u16* Bs = As + 8192;
            COMPUTE()
        }
        __builtin_amdgcn_s_barrier();   // buf(t&1) fully consumed
        __builtin_amdgcn_sched_barrier(0);
        if (t < 30) {
            STAGE(t + 2, (t & 1) * 20480)
        }
    }
    // tile 31 (buf 1): everything must be in
    asm volatile("s_waitcnt vmcnt(0)" ::: "memory");
    __builtin_amdgcn_sched_barrier(0);
    __builtin_amdgcn_s_barrier();
    {
        const u16* As = Sm + 10240;
        const u16* Bs = As + 8192;
        COMPUTE()
    }
#undef COMPUTE
#undef MFMA_ROW
#undef STAGE

#define EPI_ROW(MT) { \
    int gr0 = m0 + wm * 128 + MT * 16 + lk * 4; \
    epi_frag<MODE>(a##MT##_0, gr0, n0 + wn * 32 +  0 + lr, qo, gko, ko, vo, sgo, bg, out); \
    epi_frag<MODE>(a##MT##_1, gr0, n0 + wn * 32 + 16 + lr, qo, gko, ko, vo, sgo, bg, out); }
    EPI_ROW(0) EPI_ROW(1) EPI_ROW(2) EPI_ROW(3)
    EPI_ROW(4) EPI_ROW(5) EPI_ROW(6) EPI_ROW(7)
#undef EPI_ROW
}

// ---------------- pass1: per-chunk increment M_c = sum_s k_s e^{G_C - G_s} v_s^T ----------------
__global__ __launch_bounds__(64) void k_pass1(const u16* __restrict__ gkb,
                                              const u16* __restrict__ kb,
                                              const u16* __restrict__ vb,
                                              float* __restrict__ Mo,
                                              float* __restrict__ eGC) {
    __shared__ __align__(16) float kkT[64 * 32];  // [t][i] fp32
    int bhc = blockIdx.x;
    int c = bhc & 127, bh = bhc >> 7;
    int h = bh & 15, b = bh >> 4;
    int m0 = b * LSEQ + c * 64;
    int lane = threadIdx.x;
    if (lane < 32) {
        int i = lane;
        size_t base = (size_t)m0 * 512 + h * 32 + i;
        float G = 0.f;
        for (int t = 0; t < 64; t++) {
            G += h2f(gkb[base + (size_t)t * 512]);
            G = fmaxf(G, -60.f);
            kkT[t * 32 + i] = h2f(kb[base + (size_t)t * 512]) * __expf(-G);
        }
        eGC[bhc * 32 + i] = __expf(G);
    }
    __syncthreads();
    float Ma[32];
#pragma unroll
    for (int i = 0; i < 32; i++) Ma[i] = 0.f;
    size_t vbase = (size_t)m0 * 1024 + h * 64 + lane;
    for (int t = 0; t < 64; t++) {
        float vj = h2f(vb[vbase + (size_t)t * 1024]);
#pragma unroll
        for (int i4 = 0; i4 < 32; i4 += 4) {
            f32x4 kk4 = *(const f32x4*)&kkT[t * 32 + i4];
            Ma[i4 + 0] += kk4[0] * vj;
            Ma[i4 + 1] += kk4[1] * vj;
            Ma[i4 + 2] += kk4[2] * vj;
            Ma[i4 + 3] += kk4[3] * vj;
        }
    }
    size_t mb = (size_t)bhc * 2048 + lane;
#pragma unroll
    for (int i = 0; i < 32; i++) Mo[mb + i * 64] = Ma[i];
}

// ---------------- pass2: chunk-level recurrence, i-rows split across 4 blocks ----------------
__global__ __launch_bounds__(64) void k_pass2(float* Mbuf, float* Sbuf,
                                              const float* __restrict__ eGC,
                                              float* __restrict__ state_out, int aliased) {
    int blk = blockIdx.x;
    int bh = blk >> 2, iq = blk & 3;
    int i0 = iq * 8;
    int j = threadIdx.x;
    float S[8];
#pragma unroll
    for (int i = 0; i < 8; i++) S[i] = 0.f;
    for (int c = 0; c < NCH; c++) {
        size_t base = ((size_t)bh * NCH + c) * 2048;
        float mv[8], ev[8];
#pragma unroll
        for (int i = 0; i < 8; i++) mv[i] = Mbuf[base + (i0 + i) * 64 + j];
#pragma unroll
        for (int i = 0; i < 8; i++) ev[i] = eGC[(bh * NCH + c) * 32 + i0 + i];
        if (aliased) { asm volatile("s_waitcnt vmcnt(0)" ::: "memory"); }
#pragma unroll
        for (int i = 0; i < 8; i++) Sbuf[base + (i0 + i) * 64 + j] = S[i];  // chunk-START state
#pragma unroll
        for (int i = 0; i < 8; i++) S[i] = (S[i] + mv[i]) * ev[i];
    }
    size_t so = (size_t)bh * 2048 + j;
#pragma unroll
    for (int i = 0; i < 8; i++) state_out[so + (i0 + i) * 64] = S[i];
}

// ---------------- pass3: intra-chunk outputs + aug + groupnorm + silu-gate ----------------
// R19 post-mortem: 4-wave split ADDED 50% redundant VALU work -> VALUBusy 64%,
// pass3 557->740us. REVERT to R14 1-wave structure; fix the actual stall
// (per-iter vj/sgj global-load latency) with depth-1 software prefetch (G7),
// in both the serial-G phase and the main t-loop. No redundant work added.
__global__ __launch_bounds__(64) void k_pass3(const u16* __restrict__ qb,
                                              const u16* __restrict__ gkb,
                                              const u16* __restrict__ kb,
                                              const u16* __restrict__ vb,
                                              const u16* __restrict__ sgb,
                                              const float* __restrict__ Sbuf,
                                              const float* __restrict__ aug,
                                              u16* __restrict__ PRE) {
    __shared__ __align__(16) u16 qqT[64 * 32];  // [t][i] f16
    __shared__ __align__(16) u16 kkT[64 * 32];
    __shared__ float awl[64];
    int bhc = blockIdx.x;
    int c = bhc & 127, bh = bhc >> 7;
    int h = bh & 15, b = bh >> 4;
    int m0 = b * LSEQ + c * 64;
    int lane = threadIdx.x;
    const float scale = 0.17677669529663689f;  // 1/sqrt(32)
    // phase 1a: serial-G transform (32 lanes) with depth-1 prefetch
    if (lane < 32) {
        int i = lane;
        size_t base = (size_t)m0 * 512 + h * 32 + i;
        float G = 0.f;
        u16 gk_n = gkb[base], q_n = qb[base], k_n = kb[base];
        for (int t = 0; t < 64; t++) {
            float gkv = h2f(gk_n);
            float qv  = h2f(q_n);
            float kv  = h2f(k_n);
            if (t < 63) {
                size_t nx = base + (size_t)(t + 1) * 512;
                gk_n = gkb[nx]; q_n = qb[nx]; k_n = kb[nx];
            }
            G += gkv;
            G = fmaxf(G, -60.f);
            qqT[t * 32 + i] = f2h(qv * __expf(G) * scale);
            kkT[t * 32 + i] = f2h(kv * __expf(-G));
        }
    }
    // phase 1b: aug weights, all 64 lanes, 2 t's per iteration, prefetched
    {
        int i = lane & 31;
        int th = (lane >> 5) << 5;     // 0 or 32
        float augi = aug[h * 32 + i];
        size_t base2 = (size_t)m0 * 512 + h * 32 + i;
        u16 q_n = qb[base2 + (size_t)th * 512], k_n = kb[base2 + (size_t)th * 512];
        for (int tt = 0; tt < 32; tt++) {
            int t = tt + th;
            float qv = h2f(q_n);
            float kv = h2f(k_n);
            if (tt < 31) {
                size_t nx = base2 + (size_t)(t + 1) * 512;
                q_n = qb[nx]; k_n = kb[nx];
            }
            float p = qv * kv * augi;
            p += __shfl_xor(p, 1);
            p += __shfl_xor(p, 2);
            p += __shfl_xor(p, 4);
            p += __shfl_xor(p, 8);
            p += __shfl_xor(p, 16);
            if (i == 0) awl[t] = p;
        }
    }
    __syncthreads();
    float T[32];
    size_t sb = (size_t)bhc * 2048 + lane;
#pragma unroll
    for (int i = 0; i < 32; i++) T[i] = Sbuf[sb + i * 64];
    size_t vbase = (size_t)m0 * 1024 + h * 64 + lane;
    u16 v_n = vb[vbase], sg_n = sgb[vbase];
    for (int t = 0; t < 64; t++) {
        float vj  = h2f(v_n);
        float sgj = h2f(sg_n);
        if (t < 63) {
            size_t nx = vbase + (size_t)(t + 1) * 1024;
            v_n = vb[nx]; sg_n = sgb[nx];
        }
        float aw = awl[t];
        float o0 = 0.f, o1 = 0.f, o2 = 0.f, o3 = 0.f;
        u16x8 kk8a = *(const u16x8*)&kkT[t * 32 + 0];
        u16x8 qq8a = *(const u16x8*)&qqT[t * 32 + 0];
        u16x8 kk8b = *(const u16x8*)&kkT[t * 32 + 8];
        u16x8 qq8b = *(const u16x8*)&qqT[t * 32 + 8];
        u16x8 kk8c = *(const u16x8*)&kkT[t * 32 + 16];
        u16x8 qq8c = *(const u16x8*)&qqT[t * 32 + 16];
        u16x8 kk8d = *(const u16x8*)&kkT[t * 32 + 24];
        u16x8 qq8d = *(const u16x8*)&qqT[t * 32 + 24];
#pragma unroll
        for (int e = 0; e < 8; e++) {
            T[e]      += h2f(kk8a[e]) * vj;  o0 += h2f(qq8a[e]) * T[e];
            T[8 + e]  += h2f(kk8b[e]) * vj;  o1 += h2f(qq8b[e]) * T[8 + e];
            T[16 + e] += h2f(kk8c[e]) * vj;  o2 += h2f(qq8c[e]) * T[16 + e];
            T[24 + e] += h2f(kk8d[e]) * vj;  o3 += h2f(qq8d[e]) * T[24 + e];
        }
        float o = (o0 + o1) + (o2 + o3);
        o += 1.f / (1.f + __expf(-aw * vj));       // + sigmoid(aug_w * v)
        // group norm over dv=64 (all 64 lanes)
        float s1 = o, s2 = o * o;
#pragma unroll
        for (int msk = 1; msk < 64; msk <<= 1) {
            s1 += __shfl_xor(s1, msk);
            s2 += __shfl_xor(s2, msk);
        }
        float mu = s1 * 0.015625f;
        float var = s2 * 0.015625f - mu * mu;
        float on = (o - mu) * rsqrtf(fmaxf(var, 0.f) + 1e-5f);
        PRE[vbase + (size_t)t * 1024] = f2h(on * sgj);
    }
}

// ---------------- host launch ----------------
extern "C" void kernel_launch(void* const* d_in, const int* in_sizes, int n_in,
                              void* d_out, int out_size, void* d_ws, size_t ws_size,
                              hipStream_t stream) {
    (void)in_sizes; (void)n_in; (void)out_size;
    const float* x      = (const float*)d_in[0];
    const float* conv_w = (const float*)d_in[1];
    const float* Wq     = (const float*)d_in[2];
    const float* Wkg    = (const float*)d_in[3];
    const float* Wv     = (const float*)d_in[4];
    const float* Wg     = (const float*)d_in[5];
    const float* bg     = (const float*)d_in[6];
    const float* Wout   = (const float*)d_in[7];
    const float* aug    = (const float*)d_in[8];

    char* ws = (char*)d_ws;
    u16*   xb    = (u16*)  (ws + 0);            // 134217728 B (also PRE later)
    u16*   Wcat  = (u16*)  (ws + 134217728);    //   6291456
    u16*   WoutT = (u16*)  (ws + 140509184);    //   2097152
    u16*   qb    = (u16*)  (ws + 142606336);    //  67108864
    u16*   gkb   = (u16*)  (ws + 209715200);    //  67108864
    u16*   kbuf  = (u16*)  (ws + 276824064);    //  67108864
    u16*   sgb   = (u16*)  (ws + 343932928);    // 134217728
    float* Mbuf  = (float*)(ws + 478150656);    // 134217728
    float* eGC   = (float*)(ws + 612368384);    //   2097152
    float* Sb    = (float*)(ws + 614465536);    // 134217728 (optional)
    const size_t REQ_FULL = 748683264ull;
    int aliased = (ws_size < REQ_FULL) ? 1 : 0;
    float* Sbuf = aliased ? Mbuf : Sb;

    float* out = (float*)d_out;
    float* state_out = out + 67108864;
    u16* vb = (u16*)d_out;  // v (f16) lives in out region until GEMM2 overwrites it

    k_conv_silu<<<dim3(65536), dim3(256), 0, stream>>>(x, conv_w, xb);
    k_packW<<<dim3(16384), dim3(256), 0, stream>>>(Wq, Wkg, Wv, Wg, Wout, Wcat, WoutT);
    k_gemm_bt<1><<<dim3(12288), dim3(256), 0, stream>>>(xb, Wcat, 48,
                                                        qb, gkb, kbuf, vb, sgb, bg, nullptr);
    k_pass1<<<dim3(16384), dim3(64), 0, stream>>>(gkb, kbuf, vb, Mbuf, eGC);
    k_pass2<<<dim3(512), dim3(64), 0, stream>>>(Mbuf, Sbuf, eGC, state_out, aliased);
    k_pass3<<<dim3(16384), dim3(64), 0, stream>>>(qb, gkb, kbuf, vb, sgb, Sbuf, aug, xb /*PRE*/);
    k_gemm_bt<2><<<dim3(4096), dim3(256), 0, stream>>>(xb, WoutT, 16,
                                                       nullptr, nullptr, nullptr, nullptr, nullptr, nullptr, out);
}